// Round 2
// baseline (1250.011 us; speedup 1.0000x reference)
//
#include <hip/hip_runtime.h>
#include <hip/hip_bf16.h>

// Problem constants (from reference)
#define NN 50000      // nodes
#define NE 800000     // edges
#define NS 2          // samples
#define DIN 128
#define DNOISE 64
#define DH0 192       // DIN + DNOISE
#define DOUT 256      // D0 == D1

typedef __bf16 bf16x8 __attribute__((ext_vector_type(8)));
typedef float floatx4 __attribute__((ext_vector_type(4)));

// ---------------- CSR build ----------------

__global__ void count_kernel(const int* __restrict__ dst, int* __restrict__ cnt) {
    int i = blockIdx.x * blockDim.x + threadIdx.x;
    if (i < NE) atomicAdd(&cnt[dst[i]], 1);
}

__global__ __launch_bounds__(1024) void scan_kernel(int* __restrict__ cnt /* in: counts, out: write cursor */,
                                                    int* __restrict__ row_ptr) {
    __shared__ int buf[1024];
    __shared__ int carry_s;
    int tid = threadIdx.x;
    if (tid == 0) { carry_s = 0; row_ptr[0] = 0; }
    __syncthreads();
    for (int base = 0; base < NN; base += 1024) {
        int i = base + tid;
        int v = (i < NN) ? cnt[i] : 0;
        buf[tid] = v;
        __syncthreads();
        for (int off = 1; off < 1024; off <<= 1) {
            int t = (tid >= off) ? buf[tid - off] : 0;
            __syncthreads();
            buf[tid] += t;
            __syncthreads();
        }
        int inc = buf[tid] + carry_s;
        if (i < NN) { row_ptr[i + 1] = inc; cnt[i] = inc - v; }  // cnt becomes write cursor
        __syncthreads();
        if (tid == 1023) carry_s = inc;
        __syncthreads();
    }
}

__global__ void fill_kernel(const int* __restrict__ src, const int* __restrict__ dst,
                            int* __restrict__ cursor, int* __restrict__ col_idx) {
    int i = blockIdx.x * blockDim.x + threadIdx.x;
    if (i < NE) {
        int p = atomicAdd(&cursor[dst[i]], 1);
        col_idx[p] = src[i];
    }
}

// ---------------- W transpose + fp32->bf16 (K x 256 -> 256 x K) ----------------

__global__ void transpose_w(const float* __restrict__ W, __hip_bfloat16* __restrict__ Wt, int K) {
    int n = blockIdx.x;  // 0..255 output column of original W
    for (int k = threadIdx.x; k < K; k += blockDim.x)
        Wt[(size_t)n * K + k] = __float2bfloat16(W[(size_t)k * DOUT + n]);
}

// ---------------- Layer 0 aggregation: z0 = (1+eps0)*h0 + sum_in h0 (fp32 in, bf16 out) ----------------
// h0(s,n,dim) = dim<128 ? X[n,dim] : noise[s,n,dim-128]

__global__ __launch_bounds__(DH0) void agg0_kernel(
    const float* __restrict__ X, const float* __restrict__ noise,
    const int* __restrict__ row_ptr, const int* __restrict__ col_idx,
    const float* __restrict__ eps0p, __hip_bfloat16* __restrict__ z0) {
    int d = blockIdx.x, s = blockIdx.y, dim = threadIdx.x;
    float e0 = eps0p[0];
    const bool isX = dim < DIN;
    float self = isX ? X[(size_t)d * DIN + dim]
                     : noise[((size_t)s * NN + d) * DNOISE + (dim - DIN)];
    float acc = (1.f + e0) * self;
    int beg = row_ptr[d], end = row_ptr[d + 1];
    for (int e = beg; e < end; ++e) {
        int sn = col_idx[e];
        acc += isX ? X[(size_t)sn * DIN + dim]
                   : noise[((size_t)s * NN + sn) * DNOISE + (dim - DIN)];
    }
    z0[((size_t)s * NN + d) * DH0 + dim] = __float2bfloat16(acc);
}

// ---------------- Layer 1 aggregation: z1 = (1+eps1)*h1 + sum_in h1 (bf16 in, bf16 out) ----------------

__global__ __launch_bounds__(DOUT) void agg1_kernel(
    const __hip_bfloat16* __restrict__ h, const int* __restrict__ row_ptr, const int* __restrict__ col_idx,
    const float* __restrict__ eps1p, __hip_bfloat16* __restrict__ z1) {
    int d = blockIdx.x, s = blockIdx.y, dim = threadIdx.x;
    float e1 = eps1p[0];
    size_t rowoff = (size_t)s * NN;
    float acc = (1.f + e1) * __bfloat162float(h[(rowoff + d) * DOUT + dim]);
    int beg = row_ptr[d], end = row_ptr[d + 1];
    for (int e = beg; e < end; ++e)
        acc += __bfloat162float(h[(rowoff + col_idx[e]) * DOUT + dim]);
    z1[(rowoff + d) * DOUT + dim] = __float2bfloat16(acc);
}

// ---------------- GEMM: C = relu(A @ W + b), N fixed at 256 ----------------
// A: M x K bf16 row-major; Wt: 256 x K bf16 (W transposed); C: M x 256 (OUT_T).
// Wave computes 16 rows x 256 cols via 16 accumulators of 16x16x32 MFMA.
// Fragment layouts (m89/m120-verified): A[m=lane&15][k=quad*8+j];
// B[k=quad*8+j][n=lane&15]; D: col=lane&15, row=quad*4+reg.

__device__ inline void store_out(float* C, size_t idx, float v) { C[idx] = v; }
__device__ inline void store_out(__hip_bfloat16* C, size_t idx, float v) { C[idx] = __float2bfloat16(v); }

template <typename OUT_T>
__global__ __launch_bounds__(256) void gemm_bias_relu(
    const __hip_bfloat16* __restrict__ A, const __hip_bfloat16* __restrict__ Wt,
    const float* __restrict__ bias, OUT_T* __restrict__ C,
    int M, int K) {
    const int lane = threadIdx.x & 63;
    const int wave = threadIdx.x >> 6;
    const int rowBase = blockIdx.x * 64 + wave * 16;
    if (rowBase >= M) return;
    const int lo = lane & 15;   // A row within tile / B col / D col
    const int quad = lane >> 4;

    floatx4 acc[16];
#pragma unroll
    for (int t = 0; t < 16; ++t) acc[t] = (floatx4){0.f, 0.f, 0.f, 0.f};

    const __hip_bfloat16* arow = A + (size_t)(rowBase + lo) * K + quad * 8;
    for (int k0 = 0; k0 < K; k0 += 32) {
        bf16x8 afrag = *reinterpret_cast<const bf16x8*>(arow + k0);
#pragma unroll
        for (int t = 0; t < 16; ++t) {
            const __hip_bfloat16* wrow = Wt + (size_t)(t * 16 + lo) * K + k0 + quad * 8;
            bf16x8 bfrag = *reinterpret_cast<const bf16x8*>(wrow);
            acc[t] = __builtin_amdgcn_mfma_f32_16x16x32_bf16(afrag, bfrag, acc[t], 0, 0, 0);
        }
    }

#pragma unroll
    for (int t = 0; t < 16; ++t) {
        int col = t * 16 + lo;
        float bv = bias[col];
#pragma unroll
        for (int r = 0; r < 4; ++r) {
            int row = rowBase + quad * 4 + r;
            float v = acc[t][r] + bv;
            v = v > 0.f ? v : 0.f;
            store_out(C, (size_t)row * DOUT + col, v);
        }
    }
}

// ---------------- epsilon passthrough (output 1, fp32) ----------------

__global__ void copy_eps(const uint4* __restrict__ src, uint4* __restrict__ dst) {
    int i = blockIdx.x * blockDim.x + threadIdx.x;
    const int n16 = (NS * NN * DNOISE * 4) / 16;  // 160000 uint4
    if (i < n16) dst[i] = src[i];
}

extern "C" void kernel_launch(void* const* d_in, const int* in_sizes, int n_in,
                              void* d_out, int out_size, void* d_ws, size_t ws_size,
                              hipStream_t stream) {
    const float* X = (const float*)d_in[0];
    const float* noise = (const float*)d_in[1];
    const int* esrc = (const int*)d_in[2];
    const int* edst = (const int*)d_in[3];
    const float* W0 = (const float*)d_in[4];
    const float* b0 = (const float*)d_in[5];
    const float* W1 = (const float*)d_in[6];
    const float* b1 = (const float*)d_in[7];
    const float* eps0 = (const float*)d_in[8];
    const float* eps1 = (const float*)d_in[9];
    float* out = (float*)d_out;

    // Workspace carve (all 512B-aligned). Total ~55 MB.
    char* w = (char*)d_ws;
    auto carve = [&](size_t bytes) { char* p = w; w += (bytes + 511) & ~(size_t)511; return p; };
    int* cursor = (int*)carve((size_t)NN * 4);
    int* row_ptr = (int*)carve((size_t)(NN + 1) * 4);
    int* col_idx = (int*)carve((size_t)NE * 4);
    __hip_bfloat16* Wt0 = (__hip_bfloat16*)carve((size_t)DH0 * DOUT * 2);
    __hip_bfloat16* Wt1 = (__hip_bfloat16*)carve((size_t)DOUT * DOUT * 2);
    __hip_bfloat16* z = (__hip_bfloat16*)carve((size_t)NS * NN * DOUT * 2);  // z0 (192-wide) then z1 (256-wide)
    // h1 (bf16, 51.2 MB) staged in the fp32 d_out region (104.96 MB); final GEMM overwrites it
    __hip_bfloat16* h1 = (__hip_bfloat16*)d_out;

    const int M = NS * NN;  // 100000 rows

    hipMemsetAsync(cursor, 0, (size_t)NN * 4, stream);
    count_kernel<<<(NE + 255) / 256, 256, 0, stream>>>(edst, cursor);
    scan_kernel<<<1, 1024, 0, stream>>>(cursor, row_ptr);
    fill_kernel<<<(NE + 255) / 256, 256, 0, stream>>>(esrc, edst, cursor, col_idx);
    transpose_w<<<DOUT, 256, 0, stream>>>(W0, Wt0, DH0);
    transpose_w<<<DOUT, 256, 0, stream>>>(W1, Wt1, DOUT);

    agg0_kernel<<<dim3(NN, NS), DH0, 0, stream>>>(X, noise, row_ptr, col_idx, eps0, z);
    gemm_bias_relu<__hip_bfloat16><<<(M + 63) / 64, 256, 0, stream>>>(z, Wt0, b0, h1, M, DH0);
    agg1_kernel<<<dim3(NN, NS), DOUT, 0, stream>>>(h1, row_ptr, col_idx, eps1, z);
    gemm_bias_relu<float><<<(M + 63) / 64, 256, 0, stream>>>(z, Wt1, b1, out, M, DOUT);

    copy_eps<<<((NS * NN * DNOISE * 4 / 16) + 255) / 256, 256, 0, stream>>>(
        (const uint4*)noise, (uint4*)(out + (size_t)M * DOUT));
}

// Round 3
// 708.026 us; speedup vs baseline: 1.7655x; 1.7655x over previous
//
#include <hip/hip_runtime.h>
#include <hip/hip_bf16.h>

// Problem constants (from reference)
#define NN 50000      // nodes
#define NE 800000     // edges
#define NS 2          // samples
#define DIN 128
#define DNOISE 64
#define DH0 192       // DIN + DNOISE
#define DOUT 256      // D0 == D1

typedef __bf16 bf16x8 __attribute__((ext_vector_type(8)));
typedef float floatx4 __attribute__((ext_vector_type(4)));

// ---------------- CSR build ----------------

__global__ void count_kernel(const int* __restrict__ dst, int* __restrict__ cnt) {
    int i = blockIdx.x * blockDim.x + threadIdx.x;
    if (i < NE) atomicAdd(&cnt[dst[i]], 1);
}

__global__ __launch_bounds__(1024) void scan_kernel(int* __restrict__ cnt /* in: counts, out: write cursor */,
                                                    int* __restrict__ row_ptr) {
    __shared__ int buf[1024];
    __shared__ int carry_s;
    int tid = threadIdx.x;
    if (tid == 0) { carry_s = 0; row_ptr[0] = 0; }
    __syncthreads();
    for (int base = 0; base < NN; base += 1024) {
        int i = base + tid;
        int v = (i < NN) ? cnt[i] : 0;
        buf[tid] = v;
        __syncthreads();
        for (int off = 1; off < 1024; off <<= 1) {
            int t = (tid >= off) ? buf[tid - off] : 0;
            __syncthreads();
            buf[tid] += t;
            __syncthreads();
        }
        int inc = buf[tid] + carry_s;
        if (i < NN) { row_ptr[i + 1] = inc; cnt[i] = inc - v; }
        __syncthreads();
        if (tid == 1023) carry_s = inc;
        __syncthreads();
    }
}

__global__ void fill_kernel(const int* __restrict__ src, const int* __restrict__ dst,
                            int* __restrict__ cursor, int* __restrict__ col_idx) {
    int i = blockIdx.x * blockDim.x + threadIdx.x;
    if (i < NE) {
        int p = atomicAdd(&cursor[dst[i]], 1);
        col_idx[p] = src[i];
    }
}

// ---------------- W transpose + fp32->bf16 (K x 256 -> 256 x K) ----------------

__global__ void transpose_w(const float* __restrict__ W, __hip_bfloat16* __restrict__ Wt, int K) {
    int n = blockIdx.x;
    for (int k = threadIdx.x; k < K; k += blockDim.x)
        Wt[(size_t)n * K + k] = __float2bfloat16(W[(size_t)k * DOUT + n]);
}

// ---------------- bf16x2 pack/unpack helpers ----------------

__device__ inline float bflo(unsigned int u) { return __uint_as_float(u << 16); }
__device__ inline float bfhi(unsigned int u) { return __uint_as_float(u & 0xffff0000u); }
__device__ inline unsigned short f2bf_bits(float x) {
    __hip_bfloat16 b = __float2bfloat16(x);
    return *reinterpret_cast<unsigned short*>(&b);
}

// ---------------- Layer 0 aggregation ----------------
// One block per node d. Lanes 0-127: X part (sample-independent, written to both
// samples). Lanes 128-255: noise part, lane 128+j -> sample j>>6, dim j&63.
// Edge loop unrolled x4 for 4 concurrent gathers (latency-bound otherwise).

__global__ __launch_bounds__(256) void agg0_kernel(
    const float* __restrict__ X, const float* __restrict__ noise,
    const int* __restrict__ row_ptr, const int* __restrict__ col_idx,
    const float* __restrict__ eps0p, __hip_bfloat16* __restrict__ z0) {
    int d = blockIdx.x, tid = threadIdx.x;
    int beg = row_ptr[d], end = row_ptr[d + 1];
    float c = 1.f + eps0p[0];
    if (tid < DIN) {
        const float* src = X + tid;
        float acc = c * src[(size_t)d * DIN];
        int e = beg;
        for (; e + 3 < end; e += 4) {
            int i0 = col_idx[e], i1 = col_idx[e + 1], i2 = col_idx[e + 2], i3 = col_idx[e + 3];
            float v0 = src[(size_t)i0 * DIN], v1 = src[(size_t)i1 * DIN];
            float v2 = src[(size_t)i2 * DIN], v3 = src[(size_t)i3 * DIN];
            acc += (v0 + v1) + (v2 + v3);
        }
        for (; e < end; ++e) acc += src[(size_t)col_idx[e] * DIN];
        __hip_bfloat16 r = __float2bfloat16(acc);
        z0[(size_t)d * DH0 + tid] = r;
        z0[(size_t)(NN + d) * DH0 + tid] = r;
    } else {
        int j = tid - DIN;
        int s = j >> 6, dim = j & 63;
        const float* src = noise + (size_t)s * NN * DNOISE + dim;
        float acc = c * src[(size_t)d * DNOISE];
        int e = beg;
        for (; e + 3 < end; e += 4) {
            int i0 = col_idx[e], i1 = col_idx[e + 1], i2 = col_idx[e + 2], i3 = col_idx[e + 3];
            float v0 = src[(size_t)i0 * DNOISE], v1 = src[(size_t)i1 * DNOISE];
            float v2 = src[(size_t)i2 * DNOISE], v3 = src[(size_t)i3 * DNOISE];
            acc += (v0 + v1) + (v2 + v3);
        }
        for (; e < end; ++e) acc += src[(size_t)col_idx[e] * DNOISE];
        z0[(size_t)(s * NN + d) * DH0 + DIN + dim] = __float2bfloat16(acc);
    }
}

// ---------------- Layer 1 aggregation ----------------
// h1 is bf16; read as packed uint (2 dims per lane). One block per node:
// lanes 0-127 sample 0, lanes 128-255 sample 1. Edge loop unrolled x4.

__global__ __launch_bounds__(256) void agg1_kernel(
    const unsigned int* __restrict__ h, const int* __restrict__ row_ptr,
    const int* __restrict__ col_idx, const float* __restrict__ eps1p,
    unsigned int* __restrict__ z1) {
    const int RW = DOUT / 2;  // 128 uints per row
    int d = blockIdx.x, tid = threadIdx.x;
    int s = tid >> 7, cidx = tid & 127;
    int beg = row_ptr[d], end = row_ptr[d + 1];
    float c = 1.f + eps1p[0];
    const unsigned int* src = h + (size_t)s * NN * RW + cidx;
    unsigned int u = src[(size_t)d * RW];
    float aL = c * bflo(u), aH = c * bfhi(u);
    int e = beg;
    for (; e + 3 < end; e += 4) {
        int i0 = col_idx[e], i1 = col_idx[e + 1], i2 = col_idx[e + 2], i3 = col_idx[e + 3];
        unsigned int u0 = src[(size_t)i0 * RW], u1 = src[(size_t)i1 * RW];
        unsigned int u2 = src[(size_t)i2 * RW], u3 = src[(size_t)i3 * RW];
        aL += (bflo(u0) + bflo(u1)) + (bflo(u2) + bflo(u3));
        aH += (bfhi(u0) + bfhi(u1)) + (bfhi(u2) + bfhi(u3));
    }
    for (; e < end; ++e) {
        unsigned int ue = src[(size_t)col_idx[e] * RW];
        aL += bflo(ue); aH += bfhi(ue);
    }
    z1[(size_t)(s * NN + d) * RW + cidx] =
        (unsigned int)f2bf_bits(aL) | ((unsigned int)f2bf_bits(aH) << 16);
}

// ---------------- GEMM: C = relu(A @ W + b), N fixed at 256 ----------------
// A: M x K bf16 row-major; Wt: 256 x K bf16; C: M x 256 (OUT_T).
// Each wave: 32 rows (two 16-row tiles sharing each B fragment) x 256 cols.
// Layouts (m89/m120-verified): A[m=lane&15][k=quad*8+j]; B[k=quad*8+j][n=lane&15];
// D: col=lane&15, row=quad*4+reg.

__device__ inline void store_out(float* C, size_t idx, float v) { C[idx] = v; }
__device__ inline void store_out(__hip_bfloat16* C, size_t idx, float v) { C[idx] = __float2bfloat16(v); }

template <typename OUT_T>
__global__ __launch_bounds__(256) void gemm_bias_relu(
    const __hip_bfloat16* __restrict__ A, const __hip_bfloat16* __restrict__ Wt,
    const float* __restrict__ bias, OUT_T* __restrict__ C,
    int M, int K) {
    const int lane = threadIdx.x & 63;
    const int wave = threadIdx.x >> 6;
    const int rowBase = blockIdx.x * 128 + wave * 32;   // M % 32 == 0 for our shapes
    if (rowBase >= M) return;
    const int lo = lane & 15;
    const int quad = lane >> 4;

    floatx4 acc0[16], acc1[16];
#pragma unroll
    for (int t = 0; t < 16; ++t) {
        acc0[t] = (floatx4){0.f, 0.f, 0.f, 0.f};
        acc1[t] = (floatx4){0.f, 0.f, 0.f, 0.f};
    }

    const __hip_bfloat16* arow0 = A + (size_t)(rowBase + lo) * K + quad * 8;
    const __hip_bfloat16* arow1 = arow0 + (size_t)16 * K;
    for (int k0 = 0; k0 < K; k0 += 32) {
        bf16x8 a0 = *reinterpret_cast<const bf16x8*>(arow0 + k0);
        bf16x8 a1 = *reinterpret_cast<const bf16x8*>(arow1 + k0);
#pragma unroll
        for (int t = 0; t < 16; ++t) {
            bf16x8 b = *reinterpret_cast<const bf16x8*>(Wt + (size_t)(t * 16 + lo) * K + k0 + quad * 8);
            acc0[t] = __builtin_amdgcn_mfma_f32_16x16x32_bf16(a0, b, acc0[t], 0, 0, 0);
            acc1[t] = __builtin_amdgcn_mfma_f32_16x16x32_bf16(a1, b, acc1[t], 0, 0, 0);
        }
    }

#pragma unroll
    for (int t = 0; t < 16; ++t) {
        int col = t * 16 + lo;
        float bv = bias[col];
#pragma unroll
        for (int r = 0; r < 4; ++r) {
            int row0 = rowBase + quad * 4 + r;
            float v0 = acc0[t][r] + bv;
            store_out(C, (size_t)row0 * DOUT + col, v0 > 0.f ? v0 : 0.f);
            float v1 = acc1[t][r] + bv;
            store_out(C, (size_t)(row0 + 16) * DOUT + col, v1 > 0.f ? v1 : 0.f);
        }
    }
}

// ---------------- epsilon passthrough (output 1, fp32) ----------------

__global__ void copy_eps(const uint4* __restrict__ src, uint4* __restrict__ dst) {
    int i = blockIdx.x * blockDim.x + threadIdx.x;
    const int n16 = (NS * NN * DNOISE * 4) / 16;
    if (i < n16) dst[i] = src[i];
}

extern "C" void kernel_launch(void* const* d_in, const int* in_sizes, int n_in,
                              void* d_out, int out_size, void* d_ws, size_t ws_size,
                              hipStream_t stream) {
    const float* X = (const float*)d_in[0];
    const float* noise = (const float*)d_in[1];
    const int* esrc = (const int*)d_in[2];
    const int* edst = (const int*)d_in[3];
    const float* W0 = (const float*)d_in[4];
    const float* b0 = (const float*)d_in[5];
    const float* W1 = (const float*)d_in[6];
    const float* b1 = (const float*)d_in[7];
    const float* eps0 = (const float*)d_in[8];
    const float* eps1 = (const float*)d_in[9];
    float* out = (float*)d_out;

    char* w = (char*)d_ws;
    auto carve = [&](size_t bytes) { char* p = w; w += (bytes + 511) & ~(size_t)511; return p; };
    int* cursor = (int*)carve((size_t)NN * 4);
    int* row_ptr = (int*)carve((size_t)(NN + 1) * 4);
    int* col_idx = (int*)carve((size_t)NE * 4);
    __hip_bfloat16* Wt0 = (__hip_bfloat16*)carve((size_t)DH0 * DOUT * 2);
    __hip_bfloat16* Wt1 = (__hip_bfloat16*)carve((size_t)DOUT * DOUT * 2);
    __hip_bfloat16* z = (__hip_bfloat16*)carve((size_t)NS * NN * DOUT * 2);
    // h1 (bf16, 51.2 MB) staged in the fp32 d_out region (128 MB); final GEMM overwrites it
    __hip_bfloat16* h1 = (__hip_bfloat16*)d_out;

    const int M = NS * NN;  // 100000 rows (divisible by 32)

    hipMemsetAsync(cursor, 0, (size_t)NN * 4, stream);
    count_kernel<<<(NE + 255) / 256, 256, 0, stream>>>(edst, cursor);
    scan_kernel<<<1, 1024, 0, stream>>>(cursor, row_ptr);
    fill_kernel<<<(NE + 255) / 256, 256, 0, stream>>>(esrc, edst, cursor, col_idx);
    transpose_w<<<DOUT, 256, 0, stream>>>(W0, Wt0, DH0);
    transpose_w<<<DOUT, 256, 0, stream>>>(W1, Wt1, DOUT);

    agg0_kernel<<<NN, 256, 0, stream>>>(X, noise, row_ptr, col_idx, eps0, z);
    gemm_bias_relu<__hip_bfloat16><<<(M + 127) / 128, 256, 0, stream>>>(z, Wt0, b0, h1, M, DH0);
    agg1_kernel<<<NN, 256, 0, stream>>>((const unsigned int*)h1, row_ptr, col_idx, eps1,
                                        (unsigned int*)z);
    gemm_bias_relu<float><<<(M + 127) / 128, 256, 0, stream>>>(z, Wt1, b1, out, M, DOUT);

    copy_eps<<<((NS * NN * DNOISE * 4 / 16) + 255) / 256, 256, 0, stream>>>(
        (const uint4*)noise, (uint4*)(out + (size_t)M * DOUT));
}